// Round 12
// baseline (294.116 us; speedup 1.0000x reference)
//
#include <hip/hip_runtime.h>

#define NPTS 8192
#define KC   128
#define IFD  64
#define DL1  64
#define DL2  64
#define DL3  128
#define SPLITS 8
#define PPB  (NPTS/SPLITS)   // 1024 points per task slice
#define NTASK (KC*SPLITS)    // 1024 (center, slice) tasks
#define FPT  16              // FPS points per thread (512 threads)
#define NCONS 255            // consumer blocks (1..255)

// ---------------------------------------------------------------------------
// Single fused kernel: grid = 256 blocks x 512 thr, all resident (1 block/CU).
//   block 0      : FPS producer. R12 variant: (val,idx) carried through the
//                  wave shuffle reduce (2 regs — R9 showed no spill), ONE
//                  barrier/iter, redundant 8-candidate merge, winner coords
//                  via broadcast VECTOR load (R9's scalar s_load was the
//                  suspected +700cyc regression), fenceless atomicExch publish
//                  (R10 showed threadfence costs 0.36us/iter).
//   blocks 1..255: consumers — phase 0: F1 share + f1ctr; then static tasks
//                  t=(b-1)+255k: sentinel-poll centers with s_sleep(64)
//                  (8x less atomic-RMW pressure on the producer's publish
//                  lines than R7/R11's sleep(8)), ball-query, MLP, atomicMax.
// ---------------------------------------------------------------------------
__global__ __attribute__((amdgpu_flat_work_group_size(512, 512),
                          amdgpu_waves_per_eu(2, 2)))
void fused_kernel(const float* __restrict__ coords,
                  const float* __restrict__ features,
                  const float* __restrict__ W1,   // rows 0..2 rel, 3..66 feat
                  const float* __restrict__ b1,
                  const float* __restrict__ W2,
                  const float* __restrict__ b2,
                  const float* __restrict__ W3,
                  const float* __restrict__ b3,
                  float* centers,                  // d_out[0:384), memset 0
                  float* __restrict__ outf,        // d_out[384:), memset 0
                  float* __restrict__ F1,          // d_ws + 16 floats
                  int*   f1ctr) {                  // d_ws[0], memset 0
    __shared__ float sW1r[3 * 64];
    __shared__ float sb2[64];
    __shared__ float sb3[128];
    __shared__ unsigned short list[PPB];
    __shared__ int cnt;
    __shared__ float scc[3];
    __shared__ float h1[64 * 65];       // [point][dim], pad 65
    __shared__ float h2T[64 * 68];      // [dim][point], pad 68
    __shared__ float red[16 * 128];
    __shared__ float wvv[2][8];         // FPS per-wave max val (dbuf)
    __shared__ int   wvi[2][8];         // FPS per-wave argmax idx (dbuf)

    const int tid = threadIdx.x;
    const int b   = (int)blockIdx.x;

    if (b == 0) {
        // ================= FPS producer =================
        {
#pragma clang fp contract(off)
            float px[FPT], py[FPT], pz[FPT], dist[FPT];
#pragma unroll
            for (int i = 0; i < FPT; ++i) {
                const int n = i * 512 + tid;
                px[i] = coords[n * 3 + 0];
                py[i] = coords[n * 3 + 1];
                pz[i] = coords[n * 3 + 2];
                dist[i] = 1e10f;
            }
            float cx = coords[0], cy = coords[1], cz = coords[2];
            if (tid == 0) {
                atomicExch(&centers[0], cx);   // fire-and-forget publish
                atomicExch(&centers[1], cy);
                atomicExch(&centers[2], cz);
            }

            for (int s = 1; s < KC; ++s) {
                const int buf = s & 1;
                // --- distance update + per-thread (val,idx) argmax ---
                float bv = -1.0f;
                int   bi = 0;
#pragma unroll
                for (int i = 0; i < FPT; ++i) {
                    const float dx = px[i] - cx;
                    const float dy = py[i] - cy;
                    const float dz = pz[i] - cz;
                    const float t2 = (dx * dx + dy * dy) + dz * dz;
                    const float dm = dist[i] < t2 ? dist[i] : t2;
                    dist[i] = dm;
                    const bool win = dm > bv;      // strict > keeps lowest idx
                    bv = win ? dm : bv;
                    bi = win ? i * 512 + tid : bi;
                }
                // --- 64-lane (val,idx) argmax reduce; tie -> lower idx ---
#pragma unroll
                for (int off = 32; off > 0; off >>= 1) {
                    const float ov = __shfl_down(bv, off);
                    const int   oi = __shfl_down(bi, off);
                    const bool take = (ov > bv) || (ov == bv && oi < bi);
                    bv = take ? ov : bv;
                    bi = take ? oi : bi;
                }
                if ((tid & 63) == 0) {
                    wvv[buf][tid >> 6] = bv;
                    wvi[buf][tid >> 6] = bi;
                }
                __syncthreads();   // ONE barrier/iter; WAR covered by dbuf
                // --- all threads merge the 8 wave candidates redundantly ---
                float gv = wvv[buf][0];
                int   gi = wvi[buf][0];
#pragma unroll
                for (int w = 1; w < 8; ++w) {
                    const float v = wvv[buf][w];
                    const int   i = wvi[buf][w];
                    const bool take = (v > gv) || (v == gv && i < gi);
                    gv = take ? v : gv;
                    gi = take ? i : gi;
                }
                // --- broadcast VECTOR load of winner coords (1 txn/word) ---
                cx = coords[gi * 3 + 0];
                cy = coords[gi * 3 + 1];
                cz = coords[gi * 3 + 2];
                if (tid == 0) {
                    atomicExch(&centers[s * 3 + 0], cx);   // fire-and-forget;
                    atomicExch(&centers[s * 3 + 1], cy);   // drain hides under
                    atomicExch(&centers[s * 3 + 2], cz);   // next UPD phase
                }
            }
        }
        return;
    }

    // ================= consumers =================
    // ---- phase 0: F1 share, then signal ----
    {
        const int d = tid & 63;
#pragma unroll
        for (int j = 0; j < 5; ++j) {
            const int rloc = j * 8 + (tid >> 6);
            const int r = (b - 1) + NCONS * rloc;
            if (r < NPTS) {
                float acc = b1[d];
                const float* frow = features + r * IFD;
#pragma unroll 8
                for (int a = 0; a < IFD; ++a) {
                    acc += frow[a] * W1[(3 + a) * DL1 + d];
                }
                F1[r * DL1 + d] = acc;
            }
        }
        __threadfence();
        __syncthreads();
        if (tid == 0) atomicAdd(f1ctr, 1);
    }

    if (tid < 192) sW1r[tid] = W1[tid];
    if (tid < 64)  sb2[tid] = b2[tid];
    if (tid < 128) sb3[tid] = b3[tid];
    __syncthreads();

    bool f1_ready = false;
    for (int k = 0;; ++k) {
        const int t = (b - 1) + NCONS * k;   // static task map, covers 0..1023
        if (t >= NTASK) break;
        const int c = t >> 3;
        const int base = (t & 7) * PPB;

        if (tid == 0) {
            float x, y, z;
            for (;;) {   // center ready <=> all three coords nonzero (normal data)
                x = atomicAdd(&centers[c * 3 + 0], 0.0f);
                y = atomicAdd(&centers[c * 3 + 1], 0.0f);
                z = atomicAdd(&centers[c * 3 + 2], 0.0f);
                if (x != 0.0f && y != 0.0f && z != 0.0f) break;
                __builtin_amdgcn_s_sleep(64);   // sleepy poll: ~8x less L2-line
            }                                    // pressure than sleep(8)
            scc[0] = x; scc[1] = y; scc[2] = z; cnt = 0;
        }
        __syncthreads();
        const float cx = scc[0], cy = scc[1], cz = scc[2];

        // ---- ball-query compaction over this task's slice ----
        {
#pragma clang fp contract(off)
            for (int j = tid; j < PPB; j += 512) {
                const int n = base + j;
                const float dx = coords[n * 3 + 0] - cx;
                const float dy = coords[n * 3 + 1] - cy;
                const float dz = coords[n * 3 + 2] - cz;
                const float d2 = (dx * dx + dy * dy) + dz * dz;
                if (sqrtf(d2) < 1.0f) {
                    const int pos = atomicAdd(&cnt, 1);
                    list[pos] = (unsigned short)n;
                }
            }
        }
        __syncthreads();
        const int count = cnt;

        if (count > 0) {
            if (!f1_ready) {   // gate first MLP use on all F1 shares landed
                if (tid == 0) {
                    while (atomicAdd(f1ctr, 0) < NCONS) __builtin_amdgcn_s_sleep(32);
                }
                __syncthreads();
                f1_ready = true;
            }
            float rmax[4] = {0.f, 0.f, 0.f, 0.f};
            const int ntiles = (count + 63) >> 6;
            for (int T = 0; T < ntiles; ++T) {
                // ---- h1: 64 pts x 64 dims; thread = (d, prow), 8 rows each ----
                {
                    const int d = tid & 63;
                    const int pr = tid >> 6;
#pragma unroll
                    for (int r = 0; r < 8; ++r) {
                        const int p = r * 8 + pr;
                        const int li = T * 64 + p;
                        const int n = (li < count) ? (int)list[li] : (int)list[0];
                        const float rx = coords[n * 3 + 0] - cx;
                        const float ry = coords[n * 3 + 1] - cy;
                        const float rz = coords[n * 3 + 2] - cz;
                        float v = F1[n * DL1 + d];
                        v += rx * sW1r[d] + ry * sW1r[64 + d] + rz * sW1r[128 + d];
                        h1[p * 65 + d] = v > 0.f ? v : 0.f;
                    }
                }
                __syncthreads();
                // ---- h2: 2x4 register blocks, stored transposed ----
                {
                    const int p0 = (tid & 31) * 2;
                    const int d0 = (tid >> 5) * 4;
                    float acc[2][4];
#pragma unroll
                    for (int a = 0; a < 2; ++a)
#pragma unroll
                        for (int j = 0; j < 4; ++j) acc[a][j] = sb2[d0 + j];
                    for (int i = 0; i < 64; ++i) {
                        const float h0 = h1[p0 * 65 + i];
                        const float hA = h1[(p0 + 1) * 65 + i];
                        const float4 w = *reinterpret_cast<const float4*>(&W2[i * DL2 + d0]);
                        acc[0][0] += h0 * w.x; acc[0][1] += h0 * w.y;
                        acc[0][2] += h0 * w.z; acc[0][3] += h0 * w.w;
                        acc[1][0] += hA * w.x; acc[1][1] += hA * w.y;
                        acc[1][2] += hA * w.z; acc[1][3] += hA * w.w;
                    }
#pragma unroll
                    for (int j = 0; j < 4; ++j) {
                        h2T[(d0 + j) * 68 + p0]     = fmaxf(acc[0][j], 0.f);
                        h2T[(d0 + j) * 68 + p0 + 1] = fmaxf(acc[1][j], 0.f);
                    }
                }
                __syncthreads();
                // ---- h3: 4x4 register blocks + running max ----
                {
                    const int p0 = (tid >> 5) * 4;
                    const int d0 = (tid & 31) * 4;
                    float acc[4][4];
#pragma unroll
                    for (int p = 0; p < 4; ++p)
#pragma unroll
                        for (int j = 0; j < 4; ++j) acc[p][j] = sb3[d0 + j];
                    for (int i = 0; i < 64; ++i) {
                        const float4 hv = *reinterpret_cast<const float4*>(&h2T[i * 68 + p0]);
                        const float4 w = *reinterpret_cast<const float4*>(&W3[i * DL3 + d0]);
                        const float hh[4] = {hv.x, hv.y, hv.z, hv.w};
#pragma unroll
                        for (int p = 0; p < 4; ++p) {
                            acc[p][0] += hh[p] * w.x;
                            acc[p][1] += hh[p] * w.y;
                            acc[p][2] += hh[p] * w.z;
                            acc[p][3] += hh[p] * w.w;
                        }
                    }
#pragma unroll
                    for (int j = 0; j < 4; ++j) {
                        float m = acc[0][j];
#pragma unroll
                        for (int p = 1; p < 4; ++p) m = fmaxf(m, acc[p][j]);
                        m = fmaxf(m, 0.f);                 // relu commutes with max
                        rmax[j] = fmaxf(rmax[j], m);
                    }
                }
                __syncthreads();
            }
            // ---- reduce over the 16 point-groups, one atomicMax per dim ----
            {
                const int pg = tid >> 5;
                const int d0 = (tid & 31) * 4;
#pragma unroll
                for (int j = 0; j < 4; ++j) red[pg * 128 + d0 + j] = rmax[j];
            }
            __syncthreads();
            if (tid < 128) {
                float m = red[tid];
#pragma unroll
                for (int pg = 1; pg < 16; ++pg) m = fmaxf(m, red[pg * 128 + tid]);
                atomicMax((int*)&outf[c * 128 + tid], __float_as_int(m));
            }
        }
    }
}

// ---------------------------------------------------------------------------
extern "C" void kernel_launch(void* const* d_in, const int* in_sizes, int n_in,
                              void* d_out, int out_size, void* d_ws, size_t ws_size,
                              hipStream_t stream) {
    (void)in_sizes; (void)n_in; (void)ws_size;
    const float* coords   = (const float*)d_in[0];
    const float* features = (const float*)d_in[1];
    const float* W1 = (const float*)d_in[2];
    const float* b1 = (const float*)d_in[3];
    const float* W2 = (const float*)d_in[4];
    const float* b2 = (const float*)d_in[5];
    const float* W3 = (const float*)d_in[6];
    const float* b3 = (const float*)d_in[7];
    float* out = (float*)d_out;
    int*   f1ctr = (int*)d_ws;                 // [0] F1 ready-counter
    float* F1    = (float*)d_ws + 16;          // 2MB F1, 64B-aligned

    // d_out zero = centers publish-sentinel + atomicMax identity (relu >= 0).
    (void)hipMemsetAsync(d_out, 0, (size_t)out_size * sizeof(float), stream);
    (void)hipMemsetAsync(d_ws, 0, sizeof(int), stream);

    fused_kernel<<<256, 512, 0, stream>>>(coords, features, W1, b1, W2, b2, W3, b3,
                                          out, out + KC * 3, F1, f1ctr);
}